// Round 1
// baseline (787.614 us; speedup 1.0000x reference)
//
#include <hip/hip_runtime.h>

// Problem constants
#define HDIM 64
#define LSEQ 2048
#define BATCH 16
#define LN_EPS 1e-5f
#define D_EPS 1e-6f

// ---------------------------------------------------------------------------
// Kernel 1: per-token preprocessing.
//   h = LayerNorm(e + MLP(e)) where e = embed[seq], MLP = relu(eW1+b1)W2+b2
//   Also stores invd[token] = 1/(h.h + D_EPS) so the scan kernel's serial
//   chain never has to compute the denominator.
// One wave (64 lanes) per token, 4 tokens per 256-thread block.
// ---------------------------------------------------------------------------
__global__ __launch_bounds__(256) void preprocess_kernel(
    const int* __restrict__ seq, const float* __restrict__ embed,
    const float* __restrict__ W1, const float* __restrict__ b1,
    const float* __restrict__ W2, const float* __restrict__ b2,
    const float* __restrict__ gamma, const float* __restrict__ beta,
    float* __restrict__ h_out, float* __restrict__ invd_out)
{
    const int w     = threadIdx.x >> 6;   // wave id within block (0..3)
    const int lane  = threadIdx.x & 63;
    const int token = blockIdx.x * 4 + w;

    __shared__ float se[4][64];     // embedding vector per token
    __shared__ float shid[4][128];  // hidden layer per token

    const int   v = seq[token];
    const float e = embed[v * HDIM + lane];
    se[w][lane] = e;
    __syncthreads();

    // hidden[j] = relu(b1[j] + sum_i e[i] * W1[i][j]); each lane does j=lane, lane+64
    float a0 = b1[lane];
    float a1 = b1[lane + 64];
#pragma unroll
    for (int i = 0; i < 64; ++i) {
        const float ei = se[w][i];
        a0 = fmaf(ei, W1[i * 128 + lane],      a0);
        a1 = fmaf(ei, W1[i * 128 + lane + 64], a1);
    }
    a0 = fmaxf(a0, 0.f);
    a1 = fmaxf(a1, 0.f);
    shid[w][lane]      = a0;
    shid[w][lane + 64] = a1;
    __syncthreads();

    // ff[i] = b2[i] + sum_k hidden[k] * W2[k][i]
    float f = b2[lane];
#pragma unroll
    for (int k = 0; k < 128; ++k)
        f = fmaf(shid[w][k], W2[k * HDIM + lane], f);

    const float x = e + f;

    // LayerNorm over the 64 lanes (population variance)
    float s1 = x, s2 = x * x;
#pragma unroll
    for (int m = 1; m < 64; m <<= 1) {
        s1 += __shfl_xor(s1, m);
        s2 += __shfl_xor(s2, m);
    }
    const float mu  = s1 * (1.0f / 64.0f);
    const float var = s2 * (1.0f / 64.0f) - mu * mu;
    const float hv  = (x - mu) / sqrtf(var + LN_EPS) * gamma[lane] + beta[lane];

    // denominator for the delta rule: 1 / (h.h + eps)
    float d = hv * hv;
#pragma unroll
    for (int m = 1; m < 64; m <<= 1) d += __shfl_xor(d, m);

    h_out[(size_t)token * HDIM + lane] = hv;
    if (lane == 0) invd_out[token] = 1.0f / (d + D_EPS);
}

// ---------------------------------------------------------------------------
// Kernel 2: the sequential delta-rule scan + output projection.
// One block of 256 threads per batch element. Rows of M are independent:
// thread (row, q) owns M[row][16q : 16q+16]. Per step:
//   vp = M[row,:].k  (16 FMAs + xor1/xor2 quad reduce)
//   dv = k[row] - vp * invd[t]
//   M[row][j] += dv * k[j]
// k for step t+1 is prefetched during step t (addresses independent of M).
// After 2047 steps the prefetched vector IS h[b, 2047] = q; ctx = M.q, then
// out = (ctx Wr + br) Wo + bo computed in LDS.
// ---------------------------------------------------------------------------
__global__ __launch_bounds__(256) void scan_kernel(
    const float* __restrict__ h, const float* __restrict__ invd,
    const float* __restrict__ Wr, const float* __restrict__ br,
    const float* __restrict__ Wo, const float* __restrict__ bo,
    float* __restrict__ out)
{
    const int b   = blockIdx.x;
    const int tid = threadIdx.x;
    const int row = tid >> 2;
    const int q   = tid & 3;

    const float* hb = h + (size_t)b * LSEQ * HDIM;
    const float* db = invd + (size_t)b * LSEQ;

    float M[16];
#pragma unroll
    for (int j = 0; j < 16; ++j) M[j] = 0.f;

    // load k for t = 0
    float kk[16];
    {
        const float4* p = (const float4*)(hb + q * 16);
        float4 a = p[0], c = p[1], d2 = p[2], e = p[3];
        kk[0]=a.x;  kk[1]=a.y;  kk[2]=a.z;  kk[3]=a.w;
        kk[4]=c.x;  kk[5]=c.y;  kk[6]=c.z;  kk[7]=c.w;
        kk[8]=d2.x; kk[9]=d2.y; kk[10]=d2.z; kk[11]=d2.w;
        kk[12]=e.x; kk[13]=e.y; kk[14]=e.z; kk[15]=e.w;
    }
    float ks = hb[row];
    float id = db[0];

    for (int t = 0; t < 2047; ++t) {
        // prefetch step t+1 (t=2046 prefetches h[b,2047] = the query vector)
        const float* nx = hb + (size_t)(t + 1) * HDIM;
        const float4* np = (const float4*)(nx + q * 16);
        const float4 n0 = np[0], n1 = np[1], n2 = np[2], n3 = np[3];
        const float  ks_n = nx[row];
        const float  id_n = db[t + 1];

        // vp = M[row,:] . k
        float acc0 = 0.f, acc1 = 0.f;
#pragma unroll
        for (int j = 0; j < 16; j += 2) {
            acc0 = fmaf(M[j],     kk[j],     acc0);
            acc1 = fmaf(M[j + 1], kk[j + 1], acc1);
        }
        float vp = acc0 + acc1;
        vp += __shfl_xor(vp, 1);
        vp += __shfl_xor(vp, 2);

        const float dv = ks - vp * id;
#pragma unroll
        for (int j = 0; j < 16; ++j) M[j] = fmaf(dv, kk[j], M[j]);

        kk[0]=n0.x;  kk[1]=n0.y;  kk[2]=n0.z;  kk[3]=n0.w;
        kk[4]=n1.x;  kk[5]=n1.y;  kk[6]=n1.z;  kk[7]=n1.w;
        kk[8]=n2.x;  kk[9]=n2.y;  kk[10]=n2.z; kk[11]=n2.w;
        kk[12]=n3.x; kk[13]=n3.y; kk[14]=n3.z; kk[15]=n3.w;
        ks = ks_n;
        id = id_n;
    }

    // ctx[row] = M[row,:] . q   (kk now holds h[b, 2047])
    float acc0 = 0.f, acc1 = 0.f;
#pragma unroll
    for (int j = 0; j < 16; j += 2) {
        acc0 = fmaf(M[j],     kk[j],     acc0);
        acc1 = fmaf(M[j + 1], kk[j + 1], acc1);
    }
    float cp = acc0 + acc1;
    cp += __shfl_xor(cp, 1);
    cp += __shfl_xor(cp, 2);

    __shared__ float cs[64];
    __shared__ float rs[64];
    if (q == 0) cs[row] = cp;
    __syncthreads();

    if (tid < 64) {
        float r = br[tid];
#pragma unroll
        for (int i = 0; i < 64; ++i) r = fmaf(cs[i], Wr[i * 64 + tid], r);
        rs[tid] = r;
    }
    __syncthreads();

    if (tid < 64) {
        float o = bo[tid];
#pragma unroll
        for (int j = 0; j < 64; ++j) o = fmaf(rs[j], Wo[j * 64 + tid], o);
        out[b * 64 + tid] = o;
    }
}

// ---------------------------------------------------------------------------
extern "C" void kernel_launch(void* const* d_in, const int* in_sizes, int n_in,
                              void* d_out, int out_size, void* d_ws, size_t ws_size,
                              hipStream_t stream)
{
    const int*   seq   = (const int*)  d_in[0];
    const float* embed = (const float*)d_in[1];
    const float* W1    = (const float*)d_in[2];
    const float* b1    = (const float*)d_in[3];
    const float* W2    = (const float*)d_in[4];
    const float* b2    = (const float*)d_in[5];
    const float* gamma = (const float*)d_in[6];
    const float* beta  = (const float*)d_in[7];
    const float* Wr    = (const float*)d_in[8];
    const float* br    = (const float*)d_in[9];
    const float* Wo    = (const float*)d_in[10];
    const float* bo    = (const float*)d_in[11];

    float* h_ws    = (float*)d_ws;                        // 16*2048*64 f32 = 8 MB
    float* invd_ws = h_ws + (size_t)BATCH * LSEQ * HDIM;  // 16*2048 f32 = 128 KB
    float* outp    = (float*)d_out;

    hipLaunchKernelGGL(preprocess_kernel, dim3(BATCH * LSEQ / 4), dim3(256), 0, stream,
                       seq, embed, W1, b1, W2, b2, gamma, beta, h_ws, invd_ws);
    hipLaunchKernelGGL(scan_kernel, dim3(BATCH), dim3(256), 0, stream,
                       h_ws, invd_ws, Wr, br, Wo, bo, outp);
}

// Round 2
// 326.581 us; speedup vs baseline: 2.4117x; 2.4117x over previous
//
#include <hip/hip_runtime.h>

// Problem constants
#define HDIM 64
#define LSEQ 2048
#define BATCH 16
#define LN_EPS 1e-5f
#define D_EPS 1e-6f

// ---------------------------------------------------------------------------
// Kernel 1: per-token preprocessing.
//   h = LayerNorm(e + MLP(e)); invd = 1/(h.h + D_EPS)
// W1/W2 staged in LDS once per block (64 KB); 32 tokens per 256-thread block.
// ---------------------------------------------------------------------------
__global__ __launch_bounds__(256) void preprocess_kernel(
    const int* __restrict__ seq, const float* __restrict__ embed,
    const float* __restrict__ W1, const float* __restrict__ b1,
    const float* __restrict__ W2, const float* __restrict__ b2,
    const float* __restrict__ gamma, const float* __restrict__ beta,
    float* __restrict__ h_out, float* __restrict__ invd_out)
{
    __shared__ float sW1[64 * 128];   // 32 KB
    __shared__ float sW2[128 * 64];   // 32 KB
    __shared__ float se[4][64];
    __shared__ float shid[4][128];

    const int tid = threadIdx.x;
    // cooperative stage of W1, W2 into LDS (float4, coalesced)
    {
        const float4* src1 = (const float4*)W1;
        const float4* src2 = (const float4*)W2;
        float4* dst1 = (float4*)sW1;
        float4* dst2 = (float4*)sW2;
#pragma unroll
        for (int i = 0; i < 8; ++i) {
            dst1[tid + 256 * i] = src1[tid + 256 * i];
            dst2[tid + 256 * i] = src2[tid + 256 * i];
        }
    }
    const int w    = tid >> 6;   // wave id (0..3)
    const int lane = tid & 63;
    const float gm  = gamma[lane], bt = beta[lane];
    const float b1a = b1[lane], b1b = b1[lane + 64], b2v = b2[lane];
    __syncthreads();

    for (int it = 0; it < 8; ++it) {
        const int token = blockIdx.x * 32 + w * 8 + it;
        const int v = seq[token];
        const float e = embed[v * HDIM + lane];
        se[w][lane] = e;
        __syncthreads();

        float a0 = b1a, a1 = b1b;
#pragma unroll
        for (int i = 0; i < 64; ++i) {
            const float ei = se[w][i];
            a0 = fmaf(ei, sW1[i * 128 + lane],      a0);
            a1 = fmaf(ei, sW1[i * 128 + 64 + lane], a1);
        }
        a0 = fmaxf(a0, 0.f);
        a1 = fmaxf(a1, 0.f);
        shid[w][lane]      = a0;
        shid[w][lane + 64] = a1;
        __syncthreads();

        float f = b2v;
#pragma unroll
        for (int k = 0; k < 128; ++k)
            f = fmaf(shid[w][k], sW2[k * HDIM + lane], f);

        const float x = e + f;

        float s1 = x, s2 = x * x;
#pragma unroll
        for (int m = 1; m < 64; m <<= 1) {
            s1 += __shfl_xor(s1, m);
            s2 += __shfl_xor(s2, m);
        }
        const float mu  = s1 * (1.0f / 64.0f);
        const float var = s2 * (1.0f / 64.0f) - mu * mu;
        const float hv  = (x - mu) / sqrtf(var + LN_EPS) * gm + bt;

        float d = hv * hv;
#pragma unroll
        for (int m = 1; m < 64; m <<= 1) d += __shfl_xor(d, m);

        h_out[(size_t)token * HDIM + lane] = hv;
        if (lane == 0) invd_out[token] = 1.0f / (d + D_EPS);
    }
}

// ---------------------------------------------------------------------------
// Kernel 2: backward vector recurrence (ctx-only reformulation of the scan).
//   r_T = q;  for t = T..1:  d = k_t.r;  ctx += d*k_t;  r -= invd_t*d*k_t
// Layout: 2 blocks x 64 threads. lane = g*8 + c; batch b = blockIdx*8+g;
// lane owns components c*8..c*8+7 of r/ctx/k. Dot reduced over the 8 lanes
// of a group via DPP quad_perm (xor1, xor2) + ds_swizzle (xor4).
// Loads double-buffered in 8-step chunks (prefetch depth ~600 cyc).
// Epilogue: out = (ctx Wr + br) Wo + bo per batch, in-block.
// ---------------------------------------------------------------------------
__device__ __forceinline__ float grp8_reduce(float d) {
    // xor1: quad_perm [1,0,3,2] = 0xB1 ; xor2: quad_perm [2,3,0,1] = 0x4E
    int di = __float_as_int(d);
    d += __int_as_float(__builtin_amdgcn_mov_dpp(di, 0xB1, 0xF, 0xF, true));
    di = __float_as_int(d);
    d += __int_as_float(__builtin_amdgcn_mov_dpp(di, 0x4E, 0xF, 0xF, true));
    // xor4 via ds_swizzle bit-mode: (4<<10)|0x1F
    d += __int_as_float(__builtin_amdgcn_ds_swizzle(__float_as_int(d), 0x101F));
    return d;
}

__global__ __launch_bounds__(64, 1) void scan_kernel(
    const float* __restrict__ h, const float* __restrict__ invd,
    const float* __restrict__ Wr, const float* __restrict__ br,
    const float* __restrict__ Wo, const float* __restrict__ bo,
    float* __restrict__ out)
{
    const int lane = threadIdx.x;
    const int g = lane >> 3;   // batch within block
    const int c = lane & 7;    // component group
    const int b = blockIdx.x * 8 + g;

    const float* hb = h + (size_t)b * LSEQ * HDIM + c * 8;
    const float* db = invd + (size_t)b * LSEQ;

    float r[8], ctx[8];
    {
        const float* qp = hb + (size_t)2047 * HDIM;
        float4 q0 = *(const float4*)qp;
        float4 q1 = *(const float4*)(qp + 4);
        r[0]=q0.x; r[1]=q0.y; r[2]=q0.z; r[3]=q0.w;
        r[4]=q1.x; r[5]=q1.y; r[6]=q1.z; r[7]=q1.w;
    }
#pragma unroll
    for (int j = 0; j < 8; ++j) ctx[j] = 0.f;

    auto step = [&](const float4& k0, const float4& k1, float iv) {
        float kx[8] = {k0.x,k0.y,k0.z,k0.w,k1.x,k1.y,k1.z,k1.w};
        float d0 = kx[0] * r[0], d1 = kx[4] * r[4];
#pragma unroll
        for (int j = 1; j < 4; ++j) {
            d0 = fmaf(kx[j],     r[j],     d0);
            d1 = fmaf(kx[4 + j], r[4 + j], d1);
        }
        float d = grp8_reduce(d0 + d1);
        const float s = d * iv;
#pragma unroll
        for (int j = 0; j < 8; ++j) {
            ctx[j] = fmaf(d, kx[j], ctx[j]);
            r[j]   = fmaf(-s, kx[j], r[j]);
        }
    };

    float4 A[8][2]; float ivA[8];
    float4 B[8][2]; float ivB[8];

    auto load_chunk = [&](int t0, float4 (&buf)[8][2], float (&ivb)[8]) {
#pragma unroll
        for (int i = 0; i < 8; ++i) {
            const float* p = hb + (size_t)(t0 + i) * HDIM;
            buf[i][0] = *(const float4*)p;
            buf[i][1] = *(const float4*)(p + 4);
        }
        float4 v0 = *(const float4*)(db + t0);
        float4 v1 = *(const float4*)(db + t0 + 4);
        ivb[0]=v0.x; ivb[1]=v0.y; ivb[2]=v0.z; ivb[3]=v0.w;
        ivb[4]=v1.x; ivb[5]=v1.y; ivb[6]=v1.z; ivb[7]=v1.w;
    };
    auto proc_chunk = [&](float4 (&buf)[8][2], float (&ivb)[8]) {
#pragma unroll
        for (int i = 7; i >= 0; --i) step(buf[i][0], buf[i][1], ivb[i]);
    };

    // prologue: steps 2046..2040 (7 steps) into A[0..6] (A[i] = step 2040+i)
#pragma unroll
    for (int i = 0; i < 7; ++i) {
        const float* p = hb + (size_t)(2040 + i) * HDIM;
        A[i][0] = *(const float4*)p;
        A[i][1] = *(const float4*)(p + 4);
        ivA[i] = db[2040 + i];
    }
    load_chunk(2032, B, ivB);   // prefetch first main chunk
#pragma unroll
    for (int i = 6; i >= 0; --i) step(A[i][0], A[i][1], ivA[i]);

    // main: chunks t0 = 2032, 2024, ..., 0 (255 chunks), two per iteration
    for (int t0 = 2032; t0 >= 16; t0 -= 16) {
        load_chunk(t0 - 8, A, ivA);
        proc_chunk(B, ivB);
        load_chunk(t0 - 16, B, ivB);
        proc_chunk(A, ivA);
    }
    proc_chunk(B, ivB);         // chunk 0

    // ---- epilogue: out[b] = (ctx Wr + br) Wo + bo ----
    __shared__ float cs[8][64];
    __shared__ float rs[64];
#pragma unroll
    for (int j = 0; j < 8; ++j) cs[g][c * 8 + j] = ctx[j];
    __syncthreads();

    const float brv = br[lane], bov = bo[lane];
    for (int bb = 0; bb < 8; ++bb) {
        float rv = brv;
#pragma unroll
        for (int i = 0; i < 64; ++i) rv = fmaf(cs[bb][i], Wr[i * HDIM + lane], rv);
        rs[lane] = rv;
        __syncthreads();
        float ov = bov;
#pragma unroll
        for (int i = 0; i < 64; ++i) ov = fmaf(rs[i], Wo[i * HDIM + lane], ov);
        out[(size_t)(blockIdx.x * 8 + bb) * HDIM + lane] = ov;
        __syncthreads();
    }
}

// ---------------------------------------------------------------------------
extern "C" void kernel_launch(void* const* d_in, const int* in_sizes, int n_in,
                              void* d_out, int out_size, void* d_ws, size_t ws_size,
                              hipStream_t stream)
{
    const int*   seq   = (const int*)  d_in[0];
    const float* embed = (const float*)d_in[1];
    const float* W1    = (const float*)d_in[2];
    const float* b1    = (const float*)d_in[3];
    const float* W2    = (const float*)d_in[4];
    const float* b2    = (const float*)d_in[5];
    const float* gamma = (const float*)d_in[6];
    const float* beta  = (const float*)d_in[7];
    const float* Wr    = (const float*)d_in[8];
    const float* br    = (const float*)d_in[9];
    const float* Wo    = (const float*)d_in[10];
    const float* bo    = (const float*)d_in[11];

    float* h_ws    = (float*)d_ws;                        // 16*2048*64 f32 = 8 MB
    float* invd_ws = h_ws + (size_t)BATCH * LSEQ * HDIM;  // 16*2048 f32 = 128 KB
    float* outp    = (float*)d_out;

    hipLaunchKernelGGL(preprocess_kernel, dim3(BATCH * LSEQ / 32), dim3(256), 0, stream,
                       seq, embed, W1, b1, W2, b2, gamma, beta, h_ws, invd_ws);
    hipLaunchKernelGGL(scan_kernel, dim3(2), dim3(64), 0, stream,
                       h_ws, invd_ws, Wr, br, Wo, bo, outp);
}

// Round 3
// 244.819 us; speedup vs baseline: 3.2171x; 1.3340x over previous
//
#include <hip/hip_runtime.h>

// Problem constants
#define HDIM 64
#define LSEQ 2048
#define BATCH 16
#define LN_EPS 1e-5f
#define D_EPS 1e-6f

// ---------------------------------------------------------------------------
// Kernel 1: per-token preprocessing (unchanged from round 2 — controlled).
//   h = LayerNorm(e + MLP(e)); invd = 1/(h.h + D_EPS)
// ---------------------------------------------------------------------------
__global__ __launch_bounds__(256) void preprocess_kernel(
    const int* __restrict__ seq, const float* __restrict__ embed,
    const float* __restrict__ W1, const float* __restrict__ b1,
    const float* __restrict__ W2, const float* __restrict__ b2,
    const float* __restrict__ gamma, const float* __restrict__ beta,
    float* __restrict__ h_out, float* __restrict__ invd_out)
{
    __shared__ float sW1[64 * 128];   // 32 KB
    __shared__ float sW2[128 * 64];   // 32 KB
    __shared__ float se[4][64];
    __shared__ float shid[4][128];

    const int tid = threadIdx.x;
    {
        const float4* src1 = (const float4*)W1;
        const float4* src2 = (const float4*)W2;
        float4* dst1 = (float4*)sW1;
        float4* dst2 = (float4*)sW2;
#pragma unroll
        for (int i = 0; i < 8; ++i) {
            dst1[tid + 256 * i] = src1[tid + 256 * i];
            dst2[tid + 256 * i] = src2[tid + 256 * i];
        }
    }
    const int w    = tid >> 6;
    const int lane = tid & 63;
    const float gm  = gamma[lane], bt = beta[lane];
    const float b1a = b1[lane], b1b = b1[lane + 64], b2v = b2[lane];
    __syncthreads();

    for (int it = 0; it < 8; ++it) {
        const int token = blockIdx.x * 32 + w * 8 + it;
        const int v = seq[token];
        const float e = embed[v * HDIM + lane];
        se[w][lane] = e;
        __syncthreads();

        float a0 = b1a, a1 = b1b;
#pragma unroll
        for (int i = 0; i < 64; ++i) {
            const float ei = se[w][i];
            a0 = fmaf(ei, sW1[i * 128 + lane],      a0);
            a1 = fmaf(ei, sW1[i * 128 + 64 + lane], a1);
        }
        a0 = fmaxf(a0, 0.f);
        a1 = fmaxf(a1, 0.f);
        shid[w][lane]      = a0;
        shid[w][lane + 64] = a1;
        __syncthreads();

        float f = b2v;
#pragma unroll
        for (int k = 0; k < 128; ++k)
            f = fmaf(shid[w][k], sW2[k * HDIM + lane], f);

        const float x = e + f;

        float s1 = x, s2 = x * x;
#pragma unroll
        for (int m = 1; m < 64; m <<= 1) {
            s1 += __shfl_xor(s1, m);
            s2 += __shfl_xor(s2, m);
        }
        const float mu  = s1 * (1.0f / 64.0f);
        const float var = s2 * (1.0f / 64.0f) - mu * mu;
        const float hv  = (x - mu) / sqrtf(var + LN_EPS) * gm + bt;

        float d = hv * hv;
#pragma unroll
        for (int m = 1; m < 64; m <<= 1) d += __shfl_xor(d, m);

        h_out[(size_t)token * HDIM + lane] = hv;
        if (lane == 0) invd_out[token] = 1.0f / (d + D_EPS);
    }
}

// ---------------------------------------------------------------------------
// Kernel 2: backward vector recurrence, DPP-only reduction (no LDS in loop).
//   r_T = q;  for t = T..1:  d = k_t.r;  ctx += d*k_t;  r -= invd_t*d*k_t
// Layout: 4 blocks x 64 threads (1 wave each). lane = g*16 + u; batch
// b = blockIdx*4 + g; lane owns components u*4..u*4+3.
// 16-lane reduce = quad_perm xor1, quad_perm xor2, row_ror:8, row_ror:4 —
// all DPP (VALU-speed), replacing round-2's ds_swizzle (~120 cyc LDS hop).
// ---------------------------------------------------------------------------
__device__ __forceinline__ float red16(float d) {
    d += __int_as_float(__builtin_amdgcn_mov_dpp(__float_as_int(d), 0xB1,  0xF, 0xF, true)); // xor1
    d += __int_as_float(__builtin_amdgcn_mov_dpp(__float_as_int(d), 0x4E,  0xF, 0xF, true)); // xor2
    d += __int_as_float(__builtin_amdgcn_mov_dpp(__float_as_int(d), 0x128, 0xF, 0xF, true)); // row_ror:8
    d += __int_as_float(__builtin_amdgcn_mov_dpp(__float_as_int(d), 0x124, 0xF, 0xF, true)); // row_ror:4
    return d;
}

__global__ __launch_bounds__(64, 1) void scan_kernel(
    const float* __restrict__ h, const float* __restrict__ invd,
    const float* __restrict__ Wr, const float* __restrict__ br,
    const float* __restrict__ Wo, const float* __restrict__ bo,
    float* __restrict__ out)
{
    const int lane = threadIdx.x;
    const int g = lane >> 4;   // batch within block (0..3)
    const int u = lane & 15;   // component group (0..15)
    const int b = blockIdx.x * 4 + g;

    const float* hb = h + (size_t)b * LSEQ * HDIM + u * 4;
    const float* db = invd + (size_t)b * LSEQ;

    float r[4], ctx[4];
    {
        float4 q0 = *(const float4*)(hb + (size_t)2047 * HDIM);
        r[0]=q0.x; r[1]=q0.y; r[2]=q0.z; r[3]=q0.w;
    }
#pragma unroll
    for (int j = 0; j < 4; ++j) ctx[j] = 0.f;

    auto step = [&](const float4& k, float iv) {
        const float kx[4] = {k.x, k.y, k.z, k.w};
        float m0 = kx[0] * r[0];
        m0 = fmaf(kx[1], r[1], m0);
        float m1 = kx[2] * r[2];
        m1 = fmaf(kx[3], r[3], m1);
        const float d = red16(m0 + m1);
        const float s = d * iv;
#pragma unroll
        for (int j = 0; j < 4; ++j) {
            ctx[j] = fmaf(d,  kx[j], ctx[j]);
            r[j]   = fmaf(-s, kx[j], r[j]);
        }
    };

    float4 A[8]; float ivA[8];
    float4 B[8]; float ivB[8];

    auto load_chunk = [&](int t0, float4 (&buf)[8], float (&ivb)[8]) {
#pragma unroll
        for (int i = 0; i < 8; ++i)
            buf[i] = *(const float4*)(hb + (size_t)(t0 + i) * HDIM);
        float4 v0 = *(const float4*)(db + t0);
        float4 v1 = *(const float4*)(db + t0 + 4);
        ivb[0]=v0.x; ivb[1]=v0.y; ivb[2]=v0.z; ivb[3]=v0.w;
        ivb[4]=v1.x; ivb[5]=v1.y; ivb[6]=v1.z; ivb[7]=v1.w;
    };
    auto proc_chunk = [&](float4 (&buf)[8], float (&ivb)[8]) {
#pragma unroll
        for (int i = 7; i >= 0; --i) step(buf[i], ivb[i]);
    };

    // prologue: steps t = 2046..2040 (7 steps)
#pragma unroll
    for (int i = 0; i < 7; ++i) {
        A[i] = *(const float4*)(hb + (size_t)(2040 + i) * HDIM);
        ivA[i] = db[2040 + i];
    }
    load_chunk(2032, B, ivB);   // prefetch first main chunk
#pragma unroll
    for (int i = 6; i >= 0; --i) step(A[i], ivA[i]);

    // main: chunks t0 = 2032, 2024, ..., 0 (255 chunks), two per iteration
    for (int t0 = 2032; t0 >= 16; t0 -= 16) {
        load_chunk(t0 - 8, A, ivA);
        proc_chunk(B, ivB);
        load_chunk(t0 - 16, B, ivB);
        proc_chunk(A, ivA);
    }
    proc_chunk(B, ivB);         // chunk t0 = 0

    // ---- epilogue: out[b] = (ctx Wr + br) Wo + bo for the block's 4 batches
    __shared__ float cs[4][64];
    __shared__ float rs[64];
#pragma unroll
    for (int j = 0; j < 4; ++j) cs[g][u * 4 + j] = ctx[j];
    __syncthreads();

    const float brv = br[lane], bov = bo[lane];
    for (int bb = 0; bb < 4; ++bb) {
        float rv = brv;
#pragma unroll
        for (int i = 0; i < 64; ++i) rv = fmaf(cs[bb][i], Wr[i * HDIM + lane], rv);
        rs[lane] = rv;
        __syncthreads();
        float ov = bov;
#pragma unroll
        for (int i = 0; i < 64; ++i) ov = fmaf(rs[i], Wo[i * HDIM + lane], ov);
        out[(size_t)(blockIdx.x * 4 + bb) * HDIM + lane] = ov;
        __syncthreads();
    }
}

// ---------------------------------------------------------------------------
extern "C" void kernel_launch(void* const* d_in, const int* in_sizes, int n_in,
                              void* d_out, int out_size, void* d_ws, size_t ws_size,
                              hipStream_t stream)
{
    const int*   seq   = (const int*)  d_in[0];
    const float* embed = (const float*)d_in[1];
    const float* W1    = (const float*)d_in[2];
    const float* b1    = (const float*)d_in[3];
    const float* W2    = (const float*)d_in[4];
    const float* b2    = (const float*)d_in[5];
    const float* gamma = (const float*)d_in[6];
    const float* beta  = (const float*)d_in[7];
    const float* Wr    = (const float*)d_in[8];
    const float* br    = (const float*)d_in[9];
    const float* Wo    = (const float*)d_in[10];
    const float* bo    = (const float*)d_in[11];

    float* h_ws    = (float*)d_ws;                        // 16*2048*64 f32 = 8 MB
    float* invd_ws = h_ws + (size_t)BATCH * LSEQ * HDIM;  // 16*2048 f32 = 128 KB
    float* outp    = (float*)d_out;

    hipLaunchKernelGGL(preprocess_kernel, dim3(BATCH * LSEQ / 32), dim3(256), 0, stream,
                       seq, embed, W1, b1, W2, b2, gamma, beta, h_ws, invd_ws);
    hipLaunchKernelGGL(scan_kernel, dim3(4), dim3(64), 0, stream,
                       h_ws, invd_ws, Wr, br, Wo, bo, outp);
}